// Round 1
// baseline (5663.730 us; speedup 1.0000x reference)
//
#include <hip/hip_runtime.h>
#include <math.h>

#define N_NODES 200000
#define N_EDGES 6400000
#define F_IN    128
#define H_HID   6
#define C_OUT   10
#define G_BATCH 64

// ---------------------------------------------------------------------------
// 1) degree histogram: deg[col[e]] += 1
__global__ void deg_kernel(const int* __restrict__ col, float* __restrict__ deg, int E) {
    int e = blockIdx.x * blockDim.x + threadIdx.x;
    if (e < E) atomicAdd(&deg[col[e]], 1.0f);
}

// 2) dis = rsqrt(deg + 1)  (in place)
__global__ void dis_kernel(float* __restrict__ deg, int n) {
    int i = blockIdx.x * blockDim.x + threadIdx.x;
    if (i < n) deg[i] = rsqrtf(deg[i] + 1.0f);
}

// 3) h1s[n][j] = dis[n] * (x[n] @ W1)[j]   (pre-scaled: edge pass needs no mults)
__global__ void xw1_kernel(const float* __restrict__ x, const float* __restrict__ W1,
                           const float* __restrict__ dis, float* __restrict__ h1s) {
    __shared__ float w[F_IN * H_HID];
    for (int i = threadIdx.x; i < F_IN * H_HID; i += blockDim.x) w[i] = W1[i];
    __syncthreads();
    int n = blockIdx.x * blockDim.x + threadIdx.x;
    if (n >= N_NODES) return;
    float acc[H_HID] = {0.f, 0.f, 0.f, 0.f, 0.f, 0.f};
    const float4* xr = (const float4*)(x + (size_t)n * F_IN);
#pragma unroll 4
    for (int f4 = 0; f4 < F_IN / 4; ++f4) {
        float4 v = xr[f4];
        int f = f4 * 4;
#pragma unroll
        for (int j = 0; j < H_HID; ++j) {
            acc[j] += v.x * w[(f + 0) * H_HID + j] + v.y * w[(f + 1) * H_HID + j]
                    + v.z * w[(f + 2) * H_HID + j] + v.w * w[(f + 3) * H_HID + j];
        }
    }
    float d = dis[n];
#pragma unroll
    for (int j = 0; j < H_HID; ++j) h1s[(size_t)n * H_HID + j] = d * acc[j];
}

// 4) conv1 edge scatter: agg1[col] += h1s[row]   (6 channels)
__global__ void edge1_kernel(const int* __restrict__ row, const int* __restrict__ col,
                             const float* __restrict__ h1s, float* __restrict__ agg1, int E) {
    int e = blockIdx.x * blockDim.x + threadIdx.x;
    if (e >= E) return;
    int r = row[e], c = col[e];
    const float2* src = (const float2*)(h1s + (size_t)r * H_HID);  // 24B offset: 8-aligned
    float2 a = src[0], b = src[1], d = src[2];
    float* dst = agg1 + (size_t)c * H_HID;
    atomicAdd(dst + 0, a.x); atomicAdd(dst + 1, a.y);
    atomicAdd(dst + 2, b.x); atomicAdd(dst + 3, b.y);
    atomicAdd(dst + 4, d.x); atomicAdd(dst + 5, d.y);
}

// 5) node update conv1 + relu + W2 matmul, pre-scaled for conv2:
//    r[j]    = relu(dis*(agg1 + h1s) + b1)
//    h2s[c]  = dis * (r @ W2)[c]
__global__ void node1_kernel(const float* __restrict__ h1s, const float* __restrict__ agg1,
                             const float* __restrict__ dis, const float* __restrict__ b1,
                             const float* __restrict__ W2, float* __restrict__ h2s) {
    __shared__ float w2[H_HID * C_OUT];
    __shared__ float b1s[H_HID];
    if (threadIdx.x < H_HID * C_OUT) w2[threadIdx.x] = W2[threadIdx.x];
    if (threadIdx.x < H_HID) b1s[threadIdx.x] = b1[threadIdx.x];
    __syncthreads();
    int n = blockIdx.x * blockDim.x + threadIdx.x;
    if (n >= N_NODES) return;
    float d = dis[n];
    float r[H_HID];
#pragma unroll
    for (int j = 0; j < H_HID; ++j) {
        float v = d * (agg1[(size_t)n * H_HID + j] + h1s[(size_t)n * H_HID + j]) + b1s[j];
        r[j] = v > 0.f ? v : 0.f;
    }
#pragma unroll
    for (int c = 0; c < C_OUT; ++c) {
        float acc = 0.f;
#pragma unroll
        for (int j = 0; j < H_HID; ++j) acc += r[j] * w2[j * C_OUT + c];
        h2s[(size_t)n * C_OUT + c] = d * acc;
    }
}

// 6) conv2 edge scatter: agg2[col] += h2s[row]   (10 channels)
__global__ void edge2_kernel(const int* __restrict__ row, const int* __restrict__ col,
                             const float* __restrict__ h2s, float* __restrict__ agg2, int E) {
    int e = blockIdx.x * blockDim.x + threadIdx.x;
    if (e >= E) return;
    int r = row[e], c = col[e];
    const float2* src = (const float2*)(h2s + (size_t)r * C_OUT);  // 40B offset: 8-aligned
    float* dst = agg2 + (size_t)c * C_OUT;
#pragma unroll
    for (int k = 0; k < 5; ++k) {
        float2 v = src[k];
        atomicAdd(dst + 2 * k + 0, v.x);
        atomicAdd(dst + 2 * k + 1, v.y);
    }
}

// 7) node update conv2 + segment-sum pool (batch is sorted -> wave-uniform fast path)
__global__ void node2_pool_kernel(const float* __restrict__ h2s, const float* __restrict__ agg2,
                                  const float* __restrict__ dis, const float* __restrict__ b2,
                                  const int* __restrict__ batch,
                                  float* __restrict__ sums, float* __restrict__ cnts) {
    int n = blockIdx.x * blockDim.x + threadIdx.x;  // grid exactly covers N (200000 % 64 == 0)
    float d = dis[n];
    int g = batch[n];
    float v[C_OUT];
#pragma unroll
    for (int c = 0; c < C_OUT; ++c)
        v[c] = d * (agg2[(size_t)n * C_OUT + c] + h2s[(size_t)n * C_OUT + c]) + b2[c];

    int g0 = __shfl(g, 0);
    unsigned long long uni = __ballot(g == g0);
    if (uni == 0xFFFFFFFFFFFFFFFFULL) {
        // whole wave in one graph: shuffle tree reduction, lane 0 does the atomics
#pragma unroll
        for (int c = 0; c < C_OUT; ++c) {
#pragma unroll
            for (int off = 32; off > 0; off >>= 1) v[c] += __shfl_down(v[c], off);
        }
        if (threadIdx.x == 0) {
#pragma unroll
            for (int c = 0; c < C_OUT; ++c) atomicAdd(&sums[g * C_OUT + c], v[c]);
            atomicAdd(&cnts[g], 64.0f);
        }
    } else {
#pragma unroll
        for (int c = 0; c < C_OUT; ++c) atomicAdd(&sums[g * C_OUT + c], v[c]);
        atomicAdd(&cnts[g], 1.0f);
    }
}

// 8) mean + log_softmax -> out [G, C]
__global__ void pool_finish_kernel(const float* __restrict__ sums, const float* __restrict__ cnts,
                                   float* __restrict__ out) {
    int g = threadIdx.x;
    if (g >= G_BATCH) return;
    float inv = 1.0f / fmaxf(cnts[g], 1.0f);
    float v[C_OUT], m = -INFINITY;
#pragma unroll
    for (int c = 0; c < C_OUT; ++c) {
        v[c] = sums[g * C_OUT + c] * inv;
        m = fmaxf(m, v[c]);
    }
    float s = 0.f;
#pragma unroll
    for (int c = 0; c < C_OUT; ++c) s += expf(v[c] - m);
    float lse = m + logf(s);
#pragma unroll
    for (int c = 0; c < C_OUT; ++c) out[g * C_OUT + c] = v[c] - lse;
}

extern "C" void kernel_launch(void* const* d_in, const int* in_sizes, int n_in,
                              void* d_out, int out_size, void* d_ws, size_t ws_size,
                              hipStream_t stream) {
    const float* x   = (const float*)d_in[0];
    const int* ei    = (const int*)d_in[1];
    const int* row   = ei;             // edge_index[0]
    const int* col   = ei + N_EDGES;   // edge_index[1]
    const int* batch = (const int*)d_in[2];
    const float* W1  = (const float*)d_in[3];
    const float* b1  = (const float*)d_in[4];
    const float* W2  = (const float*)d_in[5];
    const float* b2  = (const float*)d_in[6];
    float* out = (float*)d_out;

    // workspace layout (floats); zero-needed buffers first, contiguous:
    float* ws   = (float*)d_ws;
    float* deg  = ws;                              // N      (becomes dis in-place)
    float* agg1 = deg  + N_NODES;                  // N*6
    float* agg2 = agg1 + (size_t)N_NODES * H_HID;  // N*10
    float* sums = agg2 + (size_t)N_NODES * C_OUT;  // G*10
    float* cnts = sums + G_BATCH * C_OUT;          // G
    float* h1s  = cnts + G_BATCH;                  // N*6  (fully overwritten, no zeroing)
    float* h2s  = h1s  + (size_t)N_NODES * H_HID;  // N*10 (fully overwritten)

    size_t zero_bytes = ((size_t)N_NODES * (1 + H_HID + C_OUT) + G_BATCH * C_OUT + G_BATCH) * sizeof(float);
    hipMemsetAsync(d_ws, 0, zero_bytes, stream);

    deg_kernel <<<(N_EDGES + 255) / 256, 256, 0, stream>>>(col, deg, N_EDGES);
    dis_kernel <<<(N_NODES + 255) / 256, 256, 0, stream>>>(deg, N_NODES);
    xw1_kernel <<<(N_NODES + 255) / 256, 256, 0, stream>>>(x, W1, deg, h1s);
    edge1_kernel<<<(N_EDGES + 255) / 256, 256, 0, stream>>>(row, col, h1s, agg1, N_EDGES);
    node1_kernel<<<(N_NODES + 255) / 256, 256, 0, stream>>>(h1s, agg1, deg, b1, W2, h2s);
    edge2_kernel<<<(N_EDGES + 255) / 256, 256, 0, stream>>>(row, col, h2s, agg2, N_EDGES);
    node2_pool_kernel<<<N_NODES / 64, 64, 0, stream>>>(h2s, agg2, deg, b2, batch, sums, cnts);
    pool_finish_kernel<<<1, 64, 0, stream>>>(sums, cnts, out);
}

// Round 2
// 1066.606 us; speedup vs baseline: 5.3101x; 5.3101x over previous
//
#include <hip/hip_runtime.h>
#include <math.h>

#define N_NODES 200000
#define N_EDGES 6400000
#define F_IN    128
#define H_HID   6
#define C_OUT   10
#define G_BATCH 64
#define NBLK    ((N_NODES + 255) / 256)   // 782 scan blocks

// ---------------------------------------------------------------------------
// 1) in-degree histogram (also = deg-1 for normalization): cnt[col[e]] += 1
__global__ void count_kernel(const int* __restrict__ col, int* __restrict__ cnt, int E) {
    int e = blockIdx.x * blockDim.x + threadIdx.x;
    if (e < E) atomicAdd(&cnt[col[e]], 1);
}

// 2a) per-block sums of cnt
__global__ void scan_blocksum(const int* __restrict__ cnt, int* __restrict__ bsum) {
    __shared__ int sm[256];
    int i = blockIdx.x * 256 + threadIdx.x;
    sm[threadIdx.x] = (i < N_NODES) ? cnt[i] : 0;
    __syncthreads();
    for (int s = 128; s > 0; s >>= 1) {
        if (threadIdx.x < s) sm[threadIdx.x] += sm[threadIdx.x + s];
        __syncthreads();
    }
    if (threadIdx.x == 0) bsum[blockIdx.x] = sm[0];
}

// 2b) single-wave exclusive scan of block sums (in place)
__global__ void scan_bsum(int* __restrict__ bsum, int nb) {
    int lane = threadIdx.x;   // block = 64
    int carry = 0;
    for (int base = 0; base < nb; base += 64) {
        int i = base + lane;
        int orig = (i < nb) ? bsum[i] : 0;
        int v = orig;
#pragma unroll
        for (int off = 1; off < 64; off <<= 1) {
            int t = __shfl_up(v, off);
            if (lane >= off) v += t;
        }
        int total = __shfl(v, 63);
        if (i < nb) bsum[i] = carry + v - orig;   // exclusive
        carry += total;
    }
}

// 2c) final offsets + dis + zero cursor
__global__ void scan_final(const int* __restrict__ cnt, const int* __restrict__ bsum,
                           int* __restrict__ offs, float* __restrict__ dis,
                           int* __restrict__ cursor) {
    __shared__ int sm[256];
    int tid = threadIdx.x;
    int i = blockIdx.x * 256 + tid;
    int v = (i < N_NODES) ? cnt[i] : 0;
    sm[tid] = v;
    __syncthreads();
    // Hillis-Steele inclusive scan
    for (int off = 1; off < 256; off <<= 1) {
        int t = (tid >= off) ? sm[tid - off] : 0;
        __syncthreads();
        sm[tid] += t;
        __syncthreads();
    }
    int excl = sm[tid] - v + bsum[blockIdx.x];
    if (i < N_NODES) {
        offs[i] = excl;
        dis[i] = rsqrtf((float)v + 1.0f);   // deg incl. self-loop
        cursor[i] = 0;
        if (i == N_NODES - 1) offs[N_NODES] = excl + v;
    }
}

// 3) CSR fill: csr[offs[c] + pos] = row  (source list per destination)
__global__ void fill_kernel(const int* __restrict__ row, const int* __restrict__ col,
                            const int* __restrict__ offs, int* __restrict__ cursor,
                            int* __restrict__ csr, int E) {
    int e = blockIdx.x * blockDim.x + threadIdx.x;
    if (e >= E) return;
    int c = col[e];
    int p = atomicAdd(&cursor[c], 1);
    csr[offs[c] + p] = row[e];
}

// 4) h1s[n][j] = dis[n] * (x[n] @ W1)[j]
__global__ void xw1_kernel(const float* __restrict__ x, const float* __restrict__ W1,
                           const float* __restrict__ dis, float* __restrict__ h1s) {
    __shared__ float w[F_IN * H_HID];
    for (int i = threadIdx.x; i < F_IN * H_HID; i += blockDim.x) w[i] = W1[i];
    __syncthreads();
    int n = blockIdx.x * blockDim.x + threadIdx.x;
    if (n >= N_NODES) return;
    float acc[H_HID] = {0.f, 0.f, 0.f, 0.f, 0.f, 0.f};
    const float4* xr = (const float4*)(x + (size_t)n * F_IN);
#pragma unroll 4
    for (int f4 = 0; f4 < F_IN / 4; ++f4) {
        float4 v = xr[f4];
        int f = f4 * 4;
#pragma unroll
        for (int j = 0; j < H_HID; ++j) {
            acc[j] += v.x * w[(f + 0) * H_HID + j] + v.y * w[(f + 1) * H_HID + j]
                    + v.z * w[(f + 2) * H_HID + j] + v.w * w[(f + 3) * H_HID + j];
        }
    }
    float d = dis[n];
#pragma unroll
    for (int j = 0; j < H_HID; ++j) h1s[(size_t)n * H_HID + j] = d * acc[j];
}

// 5) gather conv1 + relu + W2, pre-scaled for conv2. One wave per node.
__global__ void gather1_kernel(const int* __restrict__ offs, const int* __restrict__ csr,
                               const float* __restrict__ h1s, const float* __restrict__ dis,
                               const float* __restrict__ b1, const float* __restrict__ W2,
                               float* __restrict__ h2s) {
    __shared__ float w2[H_HID * C_OUT];
    __shared__ float b1s[H_HID];
    if (threadIdx.x < H_HID * C_OUT) w2[threadIdx.x] = W2[threadIdx.x];
    if (threadIdx.x < H_HID) b1s[threadIdx.x] = b1[threadIdx.x];
    __syncthreads();
    int wid = threadIdx.x >> 6, lane = threadIdx.x & 63;
    int n = blockIdx.x * 4 + wid;        // N_NODES % 4 == 0, grid exactly covers
    int s = offs[n], e_end = offs[n + 1];
    float a[H_HID] = {0.f, 0.f, 0.f, 0.f, 0.f, 0.f};
    for (int e = s + lane; e < e_end; e += 64) {
        const float2* p = (const float2*)(h1s + (size_t)csr[e] * H_HID);
        float2 v0 = p[0], v1 = p[1], v2 = p[2];
        a[0] += v0.x; a[1] += v0.y; a[2] += v1.x;
        a[3] += v1.y; a[4] += v2.x; a[5] += v2.y;
    }
#pragma unroll
    for (int j = 0; j < H_HID; ++j)
#pragma unroll
        for (int off = 32; off > 0; off >>= 1) a[j] += __shfl_xor(a[j], off);
    float d = dis[n];
    float r[H_HID];
#pragma unroll
    for (int j = 0; j < H_HID; ++j) {
        float v = d * (a[j] + h1s[(size_t)n * H_HID + j]) + b1s[j];  // self: d^2*xW1
        r[j] = v > 0.f ? v : 0.f;
    }
    if (lane < C_OUT) {
        float acc = 0.f;
#pragma unroll
        for (int j = 0; j < H_HID; ++j) acc += r[j] * w2[j * C_OUT + lane];
        h2s[(size_t)n * C_OUT + lane] = d * acc;
    }
}

// 6) gather conv2 + fused pooling. One wave per node, 4 nodes per block.
__global__ void gather2_pool_kernel(const int* __restrict__ offs, const int* __restrict__ csr,
                                    const float* __restrict__ h2s, const float* __restrict__ dis,
                                    const int* __restrict__ batch, float* __restrict__ sums) {
    __shared__ float lds[4][C_OUT];
    __shared__ int lg[4];
    int wid = threadIdx.x >> 6, lane = threadIdx.x & 63;
    int n = blockIdx.x * 4 + wid;
    int s = offs[n], e_end = offs[n + 1];
    float a[C_OUT] = {0.f, 0.f, 0.f, 0.f, 0.f, 0.f, 0.f, 0.f, 0.f, 0.f};
    for (int e = s + lane; e < e_end; e += 64) {
        const float2* p = (const float2*)(h2s + (size_t)csr[e] * C_OUT);
        float2 v0 = p[0], v1 = p[1], v2 = p[2], v3 = p[3], v4 = p[4];
        a[0] += v0.x; a[1] += v0.y; a[2] += v1.x; a[3] += v1.y; a[4] += v2.x;
        a[5] += v2.y; a[6] += v3.x; a[7] += v3.y; a[8] += v4.x; a[9] += v4.y;
    }
#pragma unroll
    for (int c = 0; c < C_OUT; ++c)
#pragma unroll
        for (int off = 32; off > 0; off >>= 1) a[c] += __shfl_xor(a[c], off);
    float d = dis[n];
    if (lane < C_OUT) lds[wid][lane] = d * (a[lane] + h2s[(size_t)n * C_OUT + lane]);
    if (lane == 0) lg[wid] = batch[n];
    __syncthreads();
    if (threadIdx.x < C_OUT) {
        int c = threadIdx.x;
        int g0 = lg[0];
        if (lg[1] == g0 && lg[2] == g0 && lg[3] == g0) {
            atomicAdd(&sums[g0 * C_OUT + c], lds[0][c] + lds[1][c] + lds[2][c] + lds[3][c]);
        } else {
#pragma unroll
            for (int w = 0; w < 4; ++w) atomicAdd(&sums[lg[w] * C_OUT + c], lds[w][c]);
        }
    }
}

// 7) mean (counts via binary search on sorted batch) + b2 + log_softmax
__global__ void pool_finish_kernel(const float* __restrict__ sums, const int* __restrict__ batch,
                                   const float* __restrict__ b2, float* __restrict__ out) {
    int g = threadIdx.x;
    if (g >= G_BATCH) return;
    int lo = 0, hi = N_NODES;
    while (lo < hi) { int mid = (lo + hi) >> 1; if (batch[mid] < g) lo = mid + 1; else hi = mid; }
    int c0 = lo;
    hi = N_NODES;
    while (lo < hi) { int mid = (lo + hi) >> 1; if (batch[mid] < g + 1) lo = mid + 1; else hi = mid; }
    float inv = 1.0f / fmaxf((float)(lo - c0), 1.0f);
    float v[C_OUT], m = -INFINITY;
#pragma unroll
    for (int c = 0; c < C_OUT; ++c) {
        v[c] = sums[g * C_OUT + c] * inv + b2[c];
        m = fmaxf(m, v[c]);
    }
    float s = 0.f;
#pragma unroll
    for (int c = 0; c < C_OUT; ++c) s += expf(v[c] - m);
    float lse = m + logf(s);
#pragma unroll
    for (int c = 0; c < C_OUT; ++c) out[g * C_OUT + c] = v[c] - lse;
}

extern "C" void kernel_launch(void* const* d_in, const int* in_sizes, int n_in,
                              void* d_out, int out_size, void* d_ws, size_t ws_size,
                              hipStream_t stream) {
    const float* x   = (const float*)d_in[0];
    const int* ei    = (const int*)d_in[1];
    const int* row   = ei;
    const int* col   = ei + N_EDGES;
    const int* batch = (const int*)d_in[2];
    const float* W1  = (const float*)d_in[3];
    const float* b1  = (const float*)d_in[4];
    const float* W2  = (const float*)d_in[5];
    const float* b2  = (const float*)d_in[6];
    float* out = (float*)d_out;

    // workspace layout — zero-needed first (cnt, sums) for one memset
    char* p = (char*)d_ws;
    int*   cnt    = (int*)p;               p += (size_t)N_NODES * 4;       // [zero]
    float* sums   = (float*)p;             p += (size_t)G_BATCH * C_OUT * 4; // [zero]
    int*   cursor = (int*)p;               p += (size_t)N_NODES * 4;       // zeroed by scan_final
    int*   offs   = (int*)p;               p += (size_t)(N_NODES + 1) * 4;
    int*   bsum   = (int*)p;               p += (size_t)NBLK * 4;
    float* dis    = (float*)p;             p += (size_t)N_NODES * 4;
    float* h1s    = (float*)p;             p += (size_t)N_NODES * H_HID * 4;
    float* h2s    = (float*)p;             p += (size_t)N_NODES * C_OUT * 4;
    int*   csr    = (int*)p;               p += (size_t)N_EDGES * 4;

    hipMemsetAsync(d_ws, 0, (size_t)N_NODES * 4 + (size_t)G_BATCH * C_OUT * 4, stream);

    count_kernel   <<<(N_EDGES + 255) / 256, 256, 0, stream>>>(col, cnt, N_EDGES);
    scan_blocksum  <<<NBLK, 256, 0, stream>>>(cnt, bsum);
    scan_bsum      <<<1, 64, 0, stream>>>(bsum, NBLK);
    scan_final     <<<NBLK, 256, 0, stream>>>(cnt, bsum, offs, dis, cursor);
    fill_kernel    <<<(N_EDGES + 255) / 256, 256, 0, stream>>>(row, col, offs, cursor, csr, N_EDGES);
    xw1_kernel     <<<NBLK, 256, 0, stream>>>(x, W1, dis, h1s);
    gather1_kernel <<<N_NODES / 4, 256, 0, stream>>>(offs, csr, h1s, dis, b1, W2, h2s);
    gather2_pool_kernel<<<N_NODES / 4, 256, 0, stream>>>(offs, csr, h2s, dis, batch, sums);
    pool_finish_kernel <<<1, 64, 0, stream>>>(sums, batch, b2, out);
}

// Round 3
// 682.697 us; speedup vs baseline: 8.2961x; 1.5623x over previous
//
#include <hip/hip_runtime.h>
#include <math.h>

#define N_NODES 200000
#define N_EDGES 6400000
#define F_IN    128
#define H_HID   6
#define C_OUT   10
#define G_BATCH 64

#define TILE_E     8192                      // edges per histogram tile
#define NT         ((N_EDGES + TILE_E - 1) / TILE_E)   // 782 tiles
#define NBUCK      ((N_NODES + 1023) / 1024)           // 196 buckets of 1024 nodes
#define TOTAL_HIST (NBUCK * NT)                        // 153272
#define NSB        ((TOTAL_HIST + 255) / 256)          // 599 scan blocks

// ---------------------------------------------------------------------------
// A1) per-tile histogram over destination buckets (col >> 10). No global atomics.
__global__ void histA_kernel(const int* __restrict__ col, int* __restrict__ tileHist, int E) {
    __shared__ int h[NBUCK];
    for (int i = threadIdx.x; i < NBUCK; i += 256) h[i] = 0;
    __syncthreads();
    int t = blockIdx.x;
    int base = t * TILE_E;
    for (int k = 0; k < TILE_E; k += 256) {
        int e = base + k + threadIdx.x;
        if (e < E) atomicAdd(&h[col[e] >> 10], 1);   // LDS atomic
    }
    __syncthreads();
    for (int b = threadIdx.x; b < NBUCK; b += 256) tileHist[b * NT + t] = h[b];
}

// A2) generic 3-phase exclusive scan over tileHist (bucket-major order)
__global__ void scan_blocksum(const int* __restrict__ a, int* __restrict__ bsum, int n) {
    __shared__ int sm[256];
    int i = blockIdx.x * 256 + threadIdx.x;
    sm[threadIdx.x] = (i < n) ? a[i] : 0;
    __syncthreads();
    for (int s = 128; s > 0; s >>= 1) {
        if (threadIdx.x < s) sm[threadIdx.x] += sm[threadIdx.x + s];
        __syncthreads();
    }
    if (threadIdx.x == 0) bsum[blockIdx.x] = sm[0];
}

__global__ void scan_bsum(int* __restrict__ bsum, int nb) {
    int lane = threadIdx.x;   // block = 64
    int carry = 0;
    for (int base = 0; base < nb; base += 64) {
        int i = base + lane;
        int orig = (i < nb) ? bsum[i] : 0;
        int v = orig;
#pragma unroll
        for (int off = 1; off < 64; off <<= 1) {
            int t = __shfl_up(v, off);
            if (lane >= off) v += t;
        }
        int total = __shfl(v, 63);
        if (i < nb) bsum[i] = carry + v - orig;   // exclusive
        carry += total;
    }
}

__global__ void scan_final(int* __restrict__ a, const int* __restrict__ bsum, int n) {
    __shared__ int sm[256];
    int tid = threadIdx.x;
    int i = blockIdx.x * 256 + tid;
    int v = (i < n) ? a[i] : 0;
    sm[tid] = v;
    __syncthreads();
    for (int off = 1; off < 256; off <<= 1) {
        int t = (tid >= off) ? sm[tid - off] : 0;
        __syncthreads();
        sm[tid] += t;
        __syncthreads();
    }
    if (i < n) a[i] = sm[tid] - v + bsum[blockIdx.x];   // exclusive, in place
}

// A3) scatter edges into bucket-contiguous binned array. Slots from LDS cursors
//     within each tile's scanned reservation. Payload packed: (col&1023)<<18 | row.
__global__ void scatterA_kernel(const int* __restrict__ row, const int* __restrict__ col,
                                const int* __restrict__ scanned, int* __restrict__ binned, int E) {
    __shared__ int lbase[NBUCK];
    __shared__ int lcnt[NBUCK];
    int t = blockIdx.x;
    for (int i = threadIdx.x; i < NBUCK; i += 256) {
        lbase[i] = scanned[i * NT + t];
        lcnt[i] = 0;
    }
    __syncthreads();
    int base = t * TILE_E;
    for (int k = 0; k < TILE_E; k += 256) {
        int e = base + k + threadIdx.x;
        if (e < E) {
            int c = col[e];
            int b = c >> 10;
            int pos = atomicAdd(&lcnt[b], 1);   // LDS atomic
            binned[lbase[b] + pos] = ((c & 1023) << 18) | row[e];
        }
    }
}

// B) per-bucket CSR: LDS count -> LDS block scan -> offs/dis -> LDS-cursor placement
__global__ void passB_kernel(const int* __restrict__ scanned, const int* __restrict__ binned,
                             int* __restrict__ offs, float* __restrict__ dis,
                             int* __restrict__ csr, int E) {
    __shared__ int cnt[1024];
    __shared__ int scn[1024];
    __shared__ int cur[1024];
    int b = blockIdx.x, tid = threadIdx.x;
    int bb = scanned[b * NT];
    int be = (b + 1 < NBUCK) ? scanned[(b + 1) * NT] : E;
    cnt[tid] = 0; cur[tid] = 0;
    __syncthreads();
    for (int e = bb + tid; e < be; e += 1024)
        atomicAdd(&cnt[binned[e] >> 18], 1);
    __syncthreads();
    int v = cnt[tid];
    scn[tid] = v;
    __syncthreads();
    for (int off = 1; off < 1024; off <<= 1) {
        int t2 = (tid >= off) ? scn[tid - off] : 0;
        __syncthreads();
        scn[tid] += t2;
        __syncthreads();
    }
    int excl = scn[tid] - v;
    scn[tid] = excl;
    int n = (b << 10) + tid;
    if (n < N_NODES) {
        offs[n] = bb + excl;
        dis[n] = rsqrtf((float)v + 1.0f);   // deg incl. self-loop
    }
    if (b == NBUCK - 1 && tid == 0) offs[N_NODES] = E;
    __syncthreads();
    for (int e = bb + tid; e < be; e += 1024) {
        int p = binned[e];
        int local = p >> 18;
        int pos = atomicAdd(&cur[local], 1);   // LDS atomic
        csr[bb + scn[local] + pos] = p & 0x3FFFF;
    }
}

// ---------------------------------------------------------------------------
// h1s[n][j] = dis[n] * (x[n] @ W1)[j]
__global__ void xw1_kernel(const float* __restrict__ x, const float* __restrict__ W1,
                           const float* __restrict__ dis, float* __restrict__ h1s) {
    __shared__ float w[F_IN * H_HID];
    for (int i = threadIdx.x; i < F_IN * H_HID; i += blockDim.x) w[i] = W1[i];
    __syncthreads();
    int n = blockIdx.x * blockDim.x + threadIdx.x;
    if (n >= N_NODES) return;
    float acc[H_HID] = {0.f, 0.f, 0.f, 0.f, 0.f, 0.f};
    const float4* xr = (const float4*)(x + (size_t)n * F_IN);
#pragma unroll 4
    for (int f4 = 0; f4 < F_IN / 4; ++f4) {
        float4 v = xr[f4];
        int f = f4 * 4;
#pragma unroll
        for (int j = 0; j < H_HID; ++j) {
            acc[j] += v.x * w[(f + 0) * H_HID + j] + v.y * w[(f + 1) * H_HID + j]
                    + v.z * w[(f + 2) * H_HID + j] + v.w * w[(f + 3) * H_HID + j];
        }
    }
    float d = dis[n];
#pragma unroll
    for (int j = 0; j < H_HID; ++j) h1s[(size_t)n * H_HID + j] = d * acc[j];
}

// gather conv1 + relu + W2, pre-scaled for conv2. One wave per node.
__global__ void gather1_kernel(const int* __restrict__ offs, const int* __restrict__ csr,
                               const float* __restrict__ h1s, const float* __restrict__ dis,
                               const float* __restrict__ b1, const float* __restrict__ W2,
                               float* __restrict__ h2s) {
    __shared__ float w2[H_HID * C_OUT];
    __shared__ float b1s[H_HID];
    if (threadIdx.x < H_HID * C_OUT) w2[threadIdx.x] = W2[threadIdx.x];
    if (threadIdx.x < H_HID) b1s[threadIdx.x] = b1[threadIdx.x];
    __syncthreads();
    int wid = threadIdx.x >> 6, lane = threadIdx.x & 63;
    int n = blockIdx.x * 4 + wid;
    int s = offs[n], e_end = offs[n + 1];
    float a[H_HID] = {0.f, 0.f, 0.f, 0.f, 0.f, 0.f};
    for (int e = s + lane; e < e_end; e += 64) {
        const float2* p = (const float2*)(h1s + (size_t)csr[e] * H_HID);
        float2 v0 = p[0], v1 = p[1], v2 = p[2];
        a[0] += v0.x; a[1] += v0.y; a[2] += v1.x;
        a[3] += v1.y; a[4] += v2.x; a[5] += v2.y;
    }
#pragma unroll
    for (int j = 0; j < H_HID; ++j)
#pragma unroll
        for (int off = 32; off > 0; off >>= 1) a[j] += __shfl_xor(a[j], off);
    float d = dis[n];
    float r[H_HID];
#pragma unroll
    for (int j = 0; j < H_HID; ++j) {
        float v = d * (a[j] + h1s[(size_t)n * H_HID + j]) + b1s[j];
        r[j] = v > 0.f ? v : 0.f;
    }
    if (lane < C_OUT) {
        float acc = 0.f;
#pragma unroll
        for (int j = 0; j < H_HID; ++j) acc += r[j] * w2[j * C_OUT + lane];
        h2s[(size_t)n * C_OUT + lane] = d * acc;
    }
}

// gather conv2 + fused pooling. One wave per node, 4 nodes per block.
__global__ void gather2_pool_kernel(const int* __restrict__ offs, const int* __restrict__ csr,
                                    const float* __restrict__ h2s, const float* __restrict__ dis,
                                    const int* __restrict__ batch, float* __restrict__ sums) {
    __shared__ float lds[4][C_OUT];
    __shared__ int lg[4];
    int wid = threadIdx.x >> 6, lane = threadIdx.x & 63;
    int n = blockIdx.x * 4 + wid;
    int s = offs[n], e_end = offs[n + 1];
    float a[C_OUT] = {0.f, 0.f, 0.f, 0.f, 0.f, 0.f, 0.f, 0.f, 0.f, 0.f};
    for (int e = s + lane; e < e_end; e += 64) {
        const float2* p = (const float2*)(h2s + (size_t)csr[e] * C_OUT);
        float2 v0 = p[0], v1 = p[1], v2 = p[2], v3 = p[3], v4 = p[4];
        a[0] += v0.x; a[1] += v0.y; a[2] += v1.x; a[3] += v1.y; a[4] += v2.x;
        a[5] += v2.y; a[6] += v3.x; a[7] += v3.y; a[8] += v4.x; a[9] += v4.y;
    }
#pragma unroll
    for (int c = 0; c < C_OUT; ++c)
#pragma unroll
        for (int off = 32; off > 0; off >>= 1) a[c] += __shfl_xor(a[c], off);
    float d = dis[n];
    if (lane < C_OUT) lds[wid][lane] = d * (a[lane] + h2s[(size_t)n * C_OUT + lane]);
    if (lane == 0) lg[wid] = batch[n];
    __syncthreads();
    if (threadIdx.x < C_OUT) {
        int c = threadIdx.x;
        int g0 = lg[0];
        if (lg[1] == g0 && lg[2] == g0 && lg[3] == g0) {
            atomicAdd(&sums[g0 * C_OUT + c], lds[0][c] + lds[1][c] + lds[2][c] + lds[3][c]);
        } else {
#pragma unroll
            for (int w = 0; w < 4; ++w) atomicAdd(&sums[lg[w] * C_OUT + c], lds[w][c]);
        }
    }
}

// mean (counts via binary search on sorted batch) + b2 + log_softmax
__global__ void pool_finish_kernel(const float* __restrict__ sums, const int* __restrict__ batch,
                                   const float* __restrict__ b2, float* __restrict__ out) {
    int g = threadIdx.x;
    if (g >= G_BATCH) return;
    int lo = 0, hi = N_NODES;
    while (lo < hi) { int mid = (lo + hi) >> 1; if (batch[mid] < g) lo = mid + 1; else hi = mid; }
    int c0 = lo;
    hi = N_NODES;
    while (lo < hi) { int mid = (lo + hi) >> 1; if (batch[mid] < g + 1) lo = mid + 1; else hi = mid; }
    float inv = 1.0f / fmaxf((float)(lo - c0), 1.0f);
    float v[C_OUT], m = -INFINITY;
#pragma unroll
    for (int c = 0; c < C_OUT; ++c) {
        v[c] = sums[g * C_OUT + c] * inv + b2[c];
        m = fmaxf(m, v[c]);
    }
    float s = 0.f;
#pragma unroll
    for (int c = 0; c < C_OUT; ++c) s += expf(v[c] - m);
    float lse = m + logf(s);
#pragma unroll
    for (int c = 0; c < C_OUT; ++c) out[g * C_OUT + c] = v[c] - lse;
}

extern "C" void kernel_launch(void* const* d_in, const int* in_sizes, int n_in,
                              void* d_out, int out_size, void* d_ws, size_t ws_size,
                              hipStream_t stream) {
    const float* x   = (const float*)d_in[0];
    const int* ei    = (const int*)d_in[1];
    const int* row   = ei;
    const int* col   = ei + N_EDGES;
    const int* batch = (const int*)d_in[2];
    const float* W1  = (const float*)d_in[3];
    const float* b1  = (const float*)d_in[4];
    const float* W2  = (const float*)d_in[5];
    const float* b2  = (const float*)d_in[6];
    float* out = (float*)d_out;

    // workspace layout (all region sizes kept 8B-multiples)
    char* p = (char*)d_ws;
    float* sums     = (float*)p;  p += (size_t)G_BATCH * C_OUT * 4;      // [zero] 2560B
    int*   tileHist = (int*)p;    p += (size_t)TOTAL_HIST * 4;           // 613KB (fully written)
    int*   bsum     = (int*)p;    p += (size_t)(NSB + 1) * 4;            // 2.4KB
    int*   offs     = (int*)p;    p += (size_t)(N_NODES + 2) * 4;        // 800KB
    float* dis      = (float*)p;  p += (size_t)N_NODES * 4;              // 800KB
    int*   csr      = (int*)p;    p += (size_t)N_EDGES * 4;              // 25.6MB
    int*   binned   = (int*)p;                                           // 25.6MB, dead after passB
    float* h1s      = (float*)binned;                                    // aliases binned
    float* h2s      = (float*)(binned + (size_t)N_NODES * H_HID);        // 4.8MB in, 8-aligned

    hipMemsetAsync(sums, 0, (size_t)G_BATCH * C_OUT * 4, stream);

    histA_kernel   <<<NT, 256, 0, stream>>>(col, tileHist, N_EDGES);
    scan_blocksum  <<<NSB, 256, 0, stream>>>(tileHist, bsum, TOTAL_HIST);
    scan_bsum      <<<1, 64, 0, stream>>>(bsum, NSB);
    scan_final     <<<NSB, 256, 0, stream>>>(tileHist, bsum, TOTAL_HIST);
    scatterA_kernel<<<NT, 256, 0, stream>>>(row, col, tileHist, binned, N_EDGES);
    passB_kernel   <<<NBUCK, 1024, 0, stream>>>(tileHist, binned, offs, dis, csr, N_EDGES);
    xw1_kernel     <<<(N_NODES + 255) / 256, 256, 0, stream>>>(x, W1, dis, h1s);
    gather1_kernel <<<N_NODES / 4, 256, 0, stream>>>(offs, csr, h1s, dis, b1, W2, h2s);
    gather2_pool_kernel<<<N_NODES / 4, 256, 0, stream>>>(offs, csr, h2s, dis, batch, sums);
    pool_finish_kernel <<<1, 64, 0, stream>>>(sums, batch, b2, out);
}

// Round 4
// 488.216 us; speedup vs baseline: 11.6009x; 1.3984x over previous
//
#include <hip/hip_runtime.h>
#include <math.h>

#define N_NODES 200000
#define N_EDGES 6400000
#define F_IN    128
#define H_HID   6
#define C_OUT   10
#define G_BATCH 64

#define TILE_E     8192                      // edges per histogram tile
#define NT         ((N_EDGES + TILE_E - 1) / TILE_E)   // 782 tiles
#define NBUCK      ((N_NODES + 1023) / 1024)           // 196 buckets of 1024 nodes
#define TOTAL_HIST (NBUCK * NT)                        // 153272
#define NSB        ((TOTAL_HIST + 255) / 256)          // 599 scan blocks

// ---- bf16 helpers (RNE) ---------------------------------------------------
__device__ __forceinline__ unsigned short f2bf(float f) {
    unsigned u = __float_as_uint(f);
    u += 0x7fff + ((u >> 16) & 1);
    return (unsigned short)(u >> 16);
}
__device__ __forceinline__ unsigned pack2(float a, float b) {
    return (unsigned)f2bf(a) | ((unsigned)f2bf(b) << 16);
}
__device__ __forceinline__ float bf_lo(unsigned u) { return __uint_as_float(u << 16); }
__device__ __forceinline__ float bf_hi(unsigned u) { return __uint_as_float(u & 0xffff0000u); }

// ---------------------------------------------------------------------------
// A1) per-tile histogram over destination buckets (col >> 10). LDS atomics only.
__global__ void histA_kernel(const int* __restrict__ col, int* __restrict__ tileHist, int E) {
    __shared__ int h[NBUCK];
    for (int i = threadIdx.x; i < NBUCK; i += 256) h[i] = 0;
    __syncthreads();
    int t = blockIdx.x;
    int base = t * TILE_E;
    for (int k = 0; k < TILE_E; k += 256) {
        int e = base + k + threadIdx.x;
        if (e < E) atomicAdd(&h[col[e] >> 10], 1);
    }
    __syncthreads();
    for (int b = threadIdx.x; b < NBUCK; b += 256) tileHist[b * NT + t] = h[b];
}

// A2) 3-phase exclusive scan over tileHist (bucket-major)
__global__ void scan_blocksum(const int* __restrict__ a, int* __restrict__ bsum, int n) {
    __shared__ int sm[256];
    int i = blockIdx.x * 256 + threadIdx.x;
    sm[threadIdx.x] = (i < n) ? a[i] : 0;
    __syncthreads();
    for (int s = 128; s > 0; s >>= 1) {
        if (threadIdx.x < s) sm[threadIdx.x] += sm[threadIdx.x + s];
        __syncthreads();
    }
    if (threadIdx.x == 0) bsum[blockIdx.x] = sm[0];
}

__global__ void scan_bsum(int* __restrict__ bsum, int nb) {
    int lane = threadIdx.x;   // block = 64
    int carry = 0;
    for (int base = 0; base < nb; base += 64) {
        int i = base + lane;
        int orig = (i < nb) ? bsum[i] : 0;
        int v = orig;
#pragma unroll
        for (int off = 1; off < 64; off <<= 1) {
            int t = __shfl_up(v, off);
            if (lane >= off) v += t;
        }
        int total = __shfl(v, 63);
        if (i < nb) bsum[i] = carry + v - orig;
        carry += total;
    }
}

__global__ void scan_final(int* __restrict__ a, const int* __restrict__ bsum, int n) {
    __shared__ int sm[256];
    int tid = threadIdx.x;
    int i = blockIdx.x * 256 + tid;
    int v = (i < n) ? a[i] : 0;
    sm[tid] = v;
    __syncthreads();
    for (int off = 1; off < 256; off <<= 1) {
        int t = (tid >= off) ? sm[tid - off] : 0;
        __syncthreads();
        sm[tid] += t;
        __syncthreads();
    }
    if (i < n) a[i] = sm[tid] - v + bsum[blockIdx.x];
}

// A3) scatter edges into bucket-contiguous binned array. Packed (col&1023)<<18 | row.
__global__ void scatterA_kernel(const int* __restrict__ row, const int* __restrict__ col,
                                const int* __restrict__ scanned, int* __restrict__ binned, int E) {
    __shared__ int lbase[NBUCK];
    __shared__ int lcnt[NBUCK];
    int t = blockIdx.x;
    for (int i = threadIdx.x; i < NBUCK; i += 256) {
        lbase[i] = scanned[i * NT + t];
        lcnt[i] = 0;
    }
    __syncthreads();
    int base = t * TILE_E;
    for (int k = 0; k < TILE_E; k += 256) {
        int e = base + k + threadIdx.x;
        if (e < E) {
            int c = col[e];
            int b = c >> 10;
            int pos = atomicAdd(&lcnt[b], 1);
            binned[lbase[b] + pos] = ((c & 1023) << 18) | row[e];
        }
    }
}

// B) per-bucket CSR: LDS count -> block scan -> offs/dis -> LDS-cursor placement
__global__ void passB_kernel(const int* __restrict__ scanned, const int* __restrict__ binned,
                             int* __restrict__ offs, float* __restrict__ dis,
                             int* __restrict__ csr, int E) {
    __shared__ int cnt[1024];
    __shared__ int scn[1024];
    __shared__ int cur[1024];
    int b = blockIdx.x, tid = threadIdx.x;
    int bb = scanned[b * NT];
    int be = (b + 1 < NBUCK) ? scanned[(b + 1) * NT] : E;
    cnt[tid] = 0; cur[tid] = 0;
    __syncthreads();
    for (int e = bb + tid; e < be; e += 1024)
        atomicAdd(&cnt[binned[e] >> 18], 1);
    __syncthreads();
    int v = cnt[tid];
    scn[tid] = v;
    __syncthreads();
    for (int off = 1; off < 1024; off <<= 1) {
        int t2 = (tid >= off) ? scn[tid - off] : 0;
        __syncthreads();
        scn[tid] += t2;
        __syncthreads();
    }
    int excl = scn[tid] - v;
    scn[tid] = excl;
    int n = (b << 10) + tid;
    if (n < N_NODES) {
        offs[n] = bb + excl;
        dis[n] = rsqrtf((float)v + 1.0f);
    }
    if (b == NBUCK - 1 && tid == 0) offs[N_NODES] = E;
    __syncthreads();
    for (int e = bb + tid; e < be; e += 1024) {
        int p = binned[e];
        int local = p >> 18;
        int pos = atomicAdd(&cur[local], 1);
        csr[bb + scn[local] + pos] = p & 0x3FFFF;
    }
}

// ---------------------------------------------------------------------------
// xw1: h1b row (uint4) = { bf16(d*a0,d*a1), bf16(d*a2,d*a3), bf16(d*a4,d*a5), bits(d) }
__global__ void xw1_kernel(const float* __restrict__ x, const float* __restrict__ W1,
                           const float* __restrict__ dis, uint4* __restrict__ h1b) {
    __shared__ float w[F_IN * H_HID];
    for (int i = threadIdx.x; i < F_IN * H_HID; i += blockDim.x) w[i] = W1[i];
    __syncthreads();
    int n = blockIdx.x * blockDim.x + threadIdx.x;
    if (n >= N_NODES) return;
    float acc[H_HID] = {0.f, 0.f, 0.f, 0.f, 0.f, 0.f};
    const float4* xr = (const float4*)(x + (size_t)n * F_IN);
#pragma unroll 4
    for (int f4 = 0; f4 < F_IN / 4; ++f4) {
        float4 v = xr[f4];
        int f = f4 * 4;
#pragma unroll
        for (int j = 0; j < H_HID; ++j) {
            acc[j] += v.x * w[(f + 0) * H_HID + j] + v.y * w[(f + 1) * H_HID + j]
                    + v.z * w[(f + 2) * H_HID + j] + v.w * w[(f + 3) * H_HID + j];
        }
    }
    float d = dis[n];
    uint4 o;
    o.x = pack2(d * acc[0], d * acc[1]);
    o.y = pack2(d * acc[2], d * acc[3]);
    o.z = pack2(d * acc[4], d * acc[5]);
    o.w = __float_as_uint(d);
    h1b[n] = o;
}

// gather conv1: 16 lanes per node. One uint4 gather per edge (L2-resident 3.2MB).
// rs row = { bf16(rs0,rs1), bf16(rs2,rs3), bf16(rs4,rs5), bits(d) },  rs = d*relu(...)
__global__ void gather1_kernel(const int* __restrict__ offs, const int* __restrict__ csr,
                               const uint4* __restrict__ h1b, const float* __restrict__ b1,
                               uint4* __restrict__ rs) {
    int grp = threadIdx.x >> 4, sub = threadIdx.x & 15;
    int n = blockIdx.x * 16 + grp;
    int s = offs[n], e_end = offs[n + 1];
    float a[H_HID] = {0.f, 0.f, 0.f, 0.f, 0.f, 0.f};
    for (int e = s + sub; e < e_end; e += 16) {
        uint4 v = h1b[csr[e]];
        a[0] += bf_lo(v.x); a[1] += bf_hi(v.x);
        a[2] += bf_lo(v.y); a[3] += bf_hi(v.y);
        a[4] += bf_lo(v.z); a[5] += bf_hi(v.z);
    }
#pragma unroll
    for (int j = 0; j < H_HID; ++j)
#pragma unroll
        for (int off = 8; off > 0; off >>= 1) a[j] += __shfl_xor(a[j], off);
    uint4 self = h1b[n];
    float d = __uint_as_float(self.w);
    float sf[H_HID] = {bf_lo(self.x), bf_hi(self.x), bf_lo(self.y),
                       bf_hi(self.y), bf_lo(self.z), bf_hi(self.z)};
    float r[H_HID];
#pragma unroll
    for (int j = 0; j < H_HID; ++j) {
        float v = d * (a[j] + sf[j]) + b1[j];
        r[j] = d * (v > 0.f ? v : 0.f);    // pre-scaled for layer 2
    }
    if (sub == 0) {
        uint4 o;
        o.x = pack2(r[0], r[1]);
        o.y = pack2(r[2], r[3]);
        o.z = pack2(r[4], r[5]);
        o.w = self.w;
        rs[n] = o;
    }
}

// gather conv2 (6ch) + W2 post-aggregation + fused pooling. 16 lanes per node.
__global__ void gather2_pool_kernel(const int* __restrict__ offs, const int* __restrict__ csr,
                                    const uint4* __restrict__ rs, const float* __restrict__ W2,
                                    const int* __restrict__ batch, float* __restrict__ sums) {
    __shared__ float w2s[H_HID * C_OUT];
    __shared__ float nodeval[16][C_OUT];
    __shared__ int lg[16];
    if (threadIdx.x < H_HID * C_OUT) w2s[threadIdx.x] = W2[threadIdx.x];
    __syncthreads();
    int grp = threadIdx.x >> 4, sub = threadIdx.x & 15;
    int n = blockIdx.x * 16 + grp;
    int s = offs[n], e_end = offs[n + 1];
    float a[H_HID] = {0.f, 0.f, 0.f, 0.f, 0.f, 0.f};
    for (int e = s + sub; e < e_end; e += 16) {
        uint4 v = rs[csr[e]];
        a[0] += bf_lo(v.x); a[1] += bf_hi(v.x);
        a[2] += bf_lo(v.y); a[3] += bf_hi(v.y);
        a[4] += bf_lo(v.z); a[5] += bf_hi(v.z);
    }
#pragma unroll
    for (int j = 0; j < H_HID; ++j)
#pragma unroll
        for (int off = 8; off > 0; off >>= 1) a[j] += __shfl_xor(a[j], off);
    uint4 self = rs[n];
    float d = __uint_as_float(self.w);
    float t[H_HID] = {a[0] + bf_lo(self.x), a[1] + bf_hi(self.x), a[2] + bf_lo(self.y),
                      a[3] + bf_hi(self.y), a[4] + bf_lo(self.z), a[5] + bf_hi(self.z)};
    if (sub < C_OUT) {
        float acc = 0.f;
#pragma unroll
        for (int j = 0; j < H_HID; ++j) acc += t[j] * w2s[j * C_OUT + sub];
        nodeval[grp][sub] = d * acc;
    }
    if (sub == 0) lg[grp] = batch[n];
    __syncthreads();
    if (threadIdx.x < C_OUT) {
        int c = threadIdx.x;
        float acc = 0.f;
        int gcur = lg[0];
#pragma unroll
        for (int w = 0; w < 16; ++w) {
            if (lg[w] != gcur) {                 // rare: graph boundary inside block
                atomicAdd(&sums[gcur * C_OUT + c], acc);
                gcur = lg[w]; acc = 0.f;
            }
            acc += nodeval[w][c];
        }
        atomicAdd(&sums[gcur * C_OUT + c], acc);
    }
}

// mean (counts via binary search on sorted batch) + b2 + log_softmax
__global__ void pool_finish_kernel(const float* __restrict__ sums, const int* __restrict__ batch,
                                   const float* __restrict__ b2, float* __restrict__ out) {
    int g = threadIdx.x;
    if (g >= G_BATCH) return;
    int lo = 0, hi = N_NODES;
    while (lo < hi) { int mid = (lo + hi) >> 1; if (batch[mid] < g) lo = mid + 1; else hi = mid; }
    int c0 = lo;
    hi = N_NODES;
    while (lo < hi) { int mid = (lo + hi) >> 1; if (batch[mid] < g + 1) lo = mid + 1; else hi = mid; }
    float inv = 1.0f / fmaxf((float)(lo - c0), 1.0f);
    float v[C_OUT], m = -INFINITY;
#pragma unroll
    for (int c = 0; c < C_OUT; ++c) {
        v[c] = sums[g * C_OUT + c] * inv + b2[c];
        m = fmaxf(m, v[c]);
    }
    float s = 0.f;
#pragma unroll
    for (int c = 0; c < C_OUT; ++c) s += expf(v[c] - m);
    float lse = m + logf(s);
#pragma unroll
    for (int c = 0; c < C_OUT; ++c) out[g * C_OUT + c] = v[c] - lse;
}

extern "C" void kernel_launch(void* const* d_in, const int* in_sizes, int n_in,
                              void* d_out, int out_size, void* d_ws, size_t ws_size,
                              hipStream_t stream) {
    const float* x   = (const float*)d_in[0];
    const int* ei    = (const int*)d_in[1];
    const int* row   = ei;
    const int* col   = ei + N_EDGES;
    const int* batch = (const int*)d_in[2];
    const float* W1  = (const float*)d_in[3];
    const float* b1  = (const float*)d_in[4];
    const float* W2  = (const float*)d_in[5];
    const float* b2  = (const float*)d_in[6];
    float* out = (float*)d_out;

    // workspace layout — every region size a multiple of 16 B so h1b/rs stay 16-aligned
    char* p = (char*)d_ws;
    float* sums     = (float*)p;  p += (size_t)G_BATCH * C_OUT * 4;      // [zero] 2560B
    int*   tileHist = (int*)p;    p += (size_t)TOTAL_HIST * 4;           // 613088B (/16 ok)
    int*   bsum     = (int*)p;    p += (size_t)(NSB + 1) * 4;            // 2400B
    int*   offs     = (int*)p;    p += (size_t)(N_NODES + 4) * 4;        // 800016B
    float* dis      = (float*)p;  p += (size_t)N_NODES * 4;              // 800000B
    int*   csr      = (int*)p;    p += (size_t)N_EDGES * 4;              // 25.6MB
    int*   binned   = (int*)p;                                           // 25.6MB, dead after passB
    uint4* h1b      = (uint4*)binned;                                    // 3.2MB, aliases binned
    uint4* rs       = (uint4*)binned + N_NODES;                          // 3.2MB

    hipMemsetAsync(sums, 0, (size_t)G_BATCH * C_OUT * 4, stream);

    histA_kernel   <<<NT, 256, 0, stream>>>(col, tileHist, N_EDGES);
    scan_blocksum  <<<NSB, 256, 0, stream>>>(tileHist, bsum, TOTAL_HIST);
    scan_bsum      <<<1, 64, 0, stream>>>(bsum, NSB);
    scan_final     <<<NSB, 256, 0, stream>>>(tileHist, bsum, TOTAL_HIST);
    scatterA_kernel<<<NT, 256, 0, stream>>>(row, col, tileHist, binned, N_EDGES);
    passB_kernel   <<<NBUCK, 1024, 0, stream>>>(tileHist, binned, offs, dis, csr, N_EDGES);
    xw1_kernel     <<<(N_NODES + 255) / 256, 256, 0, stream>>>(x, W1, dis, h1b);
    gather1_kernel <<<N_NODES / 16, 256, 0, stream>>>(offs, csr, h1b, b1, rs);
    gather2_pool_kernel<<<N_NODES / 16, 256, 0, stream>>>(offs, csr, rs, W2, batch, sums);
    pool_finish_kernel <<<1, 64, 0, stream>>>(sums, batch, b2, out);
}